// Round 7
// baseline (162.923 us; speedup 1.0000x reference)
//
#include <hip/hip_runtime.h>
#include <cstdint>
#include <cstddef>

typedef _Float16 hf2   __attribute__((ext_vector_type(2)));
typedef _Float16 f16x8 __attribute__((ext_vector_type(8)));
typedef float    f32x4 __attribute__((ext_vector_type(4)));

__device__ __forceinline__ f16x8 q2h8(uint4 q) { union { uint4 q; f16x8 h; } c; c.q = q; return c.h; }
__device__ __forceinline__ hf2 pkrtz(float lo, float hi) {
    auto v = __builtin_amdgcn_cvt_pkrtz(lo, hi);
    union { decltype(v) a; hf2 b; } c; c.a = v; return c.b;
}
__device__ __forceinline__ float lreluf(float x) { return fmaxf(x, 0.01f * x); }
// elementwise lrelu(a+b) on 8 packed f16
__device__ __forceinline__ f16x8 lrelu8(uint4 a, uint4 b) {
    f16x8 s = q2h8(a) + q2h8(b);
    f16x8 m = s * (_Float16)0.01f;
    return __builtin_elementwise_max(s, m);
}

// ---------------------------------------------------------------------------
// node projection + (extra blocks) weight packing + index-format detect.
// P[r][c] = (bias) + sum_k x[r][k] * W1[koff+k][c], stored f16.
__global__ __launch_bounds__(256) void node_proj2(
    const float* __restrict__ xd, const float* __restrict__ xi,
    const float* __restrict__ W1, const float* __restrict__ b1,
    _Float16* __restrict__ Pd, _Float16* __restrict__ Pi,
    int nd, int ni, int nblk_d, int nblk_i,
    const float* __restrict__ W2, const float* __restrict__ W3,
    _Float16* __restrict__ W2f, _Float16* __restrict__ W3f,
    const unsigned* __restrict__ ew, long long nwords, int* __restrict__ flag)
{
    const int t = threadIdx.x;
    const int nproj = nblk_d + nblk_i;

    if ((int)blockIdx.x >= nproj) {
        if ((int)blockIdx.x == nproj) {
            // W2 as MFMA B-fragments: frag(nt,kt), lane l, elem i ->
            //   B[k=kt*32+8*(l>>4)+i][col=nt*16+(l&15)]
            for (int idx = t; idx < 4096; idx += 256) {
                int i  = idx & 7;
                int l  = (idx >> 3) & 63;
                int kt = (idx >> 9) & 3;
                int nt = (idx >> 11) & 1;
                int k = kt * 32 + 8 * (l >> 4) + i;
                int j = nt * 16 + (l & 15);
                W2f[idx] = (_Float16)W2[k * 32 + j];
            }
            // W3^T as MFMA A-fragment: lane l, elem i -> W3[k=8*(l>>4)+i][row=l&15]
            for (int idx = t; idx < 512; idx += 256) {
                int i = idx & 7, l = idx >> 3;
                W3f[idx] = (_Float16)W3[(8 * (l >> 4) + i) * 16 + (l & 15)];
            }
        } else if (t < 64) {
            const long long pairs = nwords / 2;
            const long long step  = pairs / 64;
            unsigned v = 0;
            for (int s = 0; s < 4; ++s) {
                long long p = (long long)t * step + (long long)s * (step / 4 + 1);
                if (p < pairs) v |= ew[2 * p + 1];
            }
            unsigned long long ball = __ballot(v != 0);
            if (t == 0) *flag = (ball == 0ULL) ? 1 : 0;
        }
        return;
    }

    __shared__ float xs[1600];
    const int c  = t & 127;
    const int ty = t >> 7;
    const bool dis = (int)blockIdx.x >= nblk_d;
    const int b = dis ? (blockIdx.x - nblk_d) : blockIdx.x;
    const int n = dis ? ni : nd;
    const float* x = dis ? xi : xd;
    const float* W = dis ? (W1 + 100 * 128) : W1;
    _Float16* P = dis ? Pi : Pd;
    const float bv = dis ? b1[c] : 0.f;
    const int r0 = b * 16;

    const long long gbase = (long long)r0 * 100;
    const long long lim   = (long long)n * 100;
    for (int idx = t; idx < 1600; idx += 256) {
        long long g = gbase + idx;
        xs[idx] = (g < lim) ? x[g] : 0.f;
    }
    __syncthreads();

    float acc[8];
#pragma unroll
    for (int i = 0; i < 8; ++i) acc[i] = bv;

    const float4* xs4 = (const float4*)xs;
#pragma unroll 5
    for (int kk = 0; kk < 25; ++kk) {
        float w0 = W[(4 * kk + 0) * 128 + c];
        float w1 = W[(4 * kk + 1) * 128 + c];
        float w2 = W[(4 * kk + 2) * 128 + c];
        float w3 = W[(4 * kk + 3) * 128 + c];
#pragma unroll
        for (int i = 0; i < 8; ++i) {
            float4 xv = xs4[(ty * 8 + i) * 25 + kk];
            acc[i] = fmaf(xv.x, w0, acc[i]);
            acc[i] = fmaf(xv.y, w1, acc[i]);
            acc[i] = fmaf(xv.z, w2, acc[i]);
            acc[i] = fmaf(xv.w, w3, acc[i]);
        }
    }
#pragma unroll
    for (int i = 0; i < 8; ++i) {
        int r = r0 + ty * 8 + i;
        if (r < n) P[(size_t)r * 128 + c] = (_Float16)acc[i];
    }
}

// ---------------------------------------------------------------------------
// Edge MLP: 256 threads = 4 waves, each wave owns 64 edges (4 tiles of 16).
// ZERO barriers. Phase A: all gathers + layer-2 MFMAs (accs in regs).
// Phase B: h2 -> wave-private LDS. Phase C: layer-3 MFMA + shfl layer-4.
// Within-wave LDS RAW ordering is compiler-handled (lgkmcnt), no drains.
__global__ __launch_bounds__(256) void edge_mlp(
    const void* __restrict__ eidx_raw,
    const _Float16* __restrict__ Pd, const _Float16* __restrict__ Pi,
    const _Float16* __restrict__ W2f, const float* __restrict__ b2,
    const _Float16* __restrict__ W3f, const float* __restrict__ b3,
    const float* __restrict__ W4, const float* __restrict__ b4,
    const int* __restrict__ flag64,
    float* __restrict__ out, int E)
{
    __shared__ __align__(16) float H2[4][64 * 36];   // 36 KB, wave-private slabs

    const int t  = threadIdx.x;
    const int l  = t & 63;
    const int w  = t >> 6;
    const int er = l & 15;
    const int cg = l >> 4;
    const int base = blockIdx.x * 256 + w * 64;
    const int e_c = min(base + l, E - 1);
    float* Hw = H2[w];

    int i0, i1;
    if (*flag64) {
        const long long* p = (const long long*)eidx_raw;
        i0 = (int)p[e_c];
        i1 = (int)p[(size_t)E + e_c];
    } else {
        const int* p = (const int*)eidx_raw;
        i0 = p[e_c];
        i1 = p[(size_t)E + e_c];
    }

    // layer-2 B-fragments and layer-3 W3^T A-fragment (L2-hit, per-wave)
    f16x8 bf0[4], bf1[4];
    {
        const uint4* W2q = (const uint4*)W2f;
#pragma unroll
        for (int kt = 0; kt < 4; ++kt) {
            bf0[kt] = q2h8(W2q[kt * 64 + l]);
            bf1[kt] = q2h8(W2q[256 + kt * 64 + l]);
        }
    }
    const f16x8 w3f = q2h8(((const uint4*)W3f)[l]);
    const float  b2v0 = b2[er], b2v1 = b2[16 + er];
    const float4 b3q  = ((const float4*)b3)[cg];
    const float4 w4q  = ((const float4*)W4)[cg];
    const float  b4v  = b4[0];

    // ---- Phase A: all 4 q-tiles: register gather + layer-2 MFMA ----
    f32x4 c0[4], c1[4];
#pragma unroll
    for (int q = 0; q < 4; ++q) {
        const int src = q * 16 + er;
        const int j0 = __shfl(i0, src, 64);
        const int j1 = __shfl(i1, src, 64);
        const uint4* rowD = (const uint4*)(Pd + (size_t)j0 * 128);
        const uint4* rowI = (const uint4*)(Pi + (size_t)j1 * 128);
        c0[q] = (f32x4){0.f, 0.f, 0.f, 0.f};
        c1[q] = (f32x4){0.f, 0.f, 0.f, 0.f};
#pragma unroll
        for (int kt = 0; kt < 4; ++kt) {
            f16x8 af = lrelu8(rowD[kt * 4 + cg], rowI[kt * 4 + cg]);
            c0[q] = __builtin_amdgcn_mfma_f32_16x16x32_f16(af, bf0[kt], c0[q], 0, 0, 0);
            c1[q] = __builtin_amdgcn_mfma_f32_16x16x32_f16(af, bf1[kt], c1[q], 0, 0, 0);
        }
    }

    // ---- Phase B: h2 = lrelu(D + b2) -> wave-private LDS ----
#pragma unroll
    for (int q = 0; q < 4; ++q)
#pragma unroll
        for (int r = 0; r < 4; ++r) {
            const int e = q * 16 + 4 * cg + r;
            Hw[e * 36 + er]      = lreluf(c0[q][r] + b2v0);
            Hw[e * 36 + 16 + er] = lreluf(c1[q][r] + b2v1);
        }

    // ---- Phase C: layer-3 MFMA (swapped operands) + layer-4 shfl reduce ----
#pragma unroll
    for (int q = 0; q < 4; ++q) {
        const int e2 = q * 16 + er;
        const float4* hr = (const float4*)&Hw[e2 * 36 + 8 * cg];
        float4 h0 = hr[0], h1 = hr[1];
        union { hf2 h[4]; f16x8 v; } u;
        u.h[0] = pkrtz(h0.x, h0.y);
        u.h[1] = pkrtz(h0.z, h0.w);
        u.h[2] = pkrtz(h1.x, h1.y);
        u.h[3] = pkrtz(h1.z, h1.w);

        // D3 = W3^T · h2^T : lane holds D3[j3=4*cg+r][edge=er]
        f32x4 d3 = __builtin_amdgcn_mfma_f32_16x16x32_f16(
            w3f, u.v, (f32x4){0.f, 0.f, 0.f, 0.f}, 0, 0, 0);

        float v = lreluf(d3[0] + b3q.x) * w4q.x;
        v      += lreluf(d3[1] + b3q.y) * w4q.y;
        v      += lreluf(d3[2] + b3q.z) * w4q.z;
        v      += lreluf(d3[3] + b3q.w) * w4q.w;
        v += __shfl_xor(v, 16, 64);
        v += __shfl_xor(v, 32, 64);

        if (cg == 0) {
            const int eo = base + q * 16 + er;
            if (eo < E) out[eo] = v + b4v;
        }
    }
}

// ---------------------------------------------------------------------------
extern "C" void kernel_launch(void* const* d_in, const int* in_sizes, int n_in,
                              void* d_out, int out_size, void* d_ws, size_t ws_size,
                              hipStream_t stream)
{
    const float* x_drug = (const float*)d_in[0];
    const float* x_dis  = (const float*)d_in[1];
    const void*  eidx   = d_in[2];
    const float* W1 = (const float*)d_in[3];
    const float* b1 = (const float*)d_in[4];
    const float* W2 = (const float*)d_in[5];
    const float* b2 = (const float*)d_in[6];
    const float* W3 = (const float*)d_in[7];
    const float* b3 = (const float*)d_in[8];
    const float* W4 = (const float*)d_in[9];
    const float* b4 = (const float*)d_in[10];

    const int nd = in_sizes[0] / 100;
    const int ni = in_sizes[1] / 100;
    const int E  = in_sizes[2] / 2;

    char* ws = (char*)d_ws;
    _Float16* Pd  = (_Float16*)ws;                   size_t off = (size_t)nd * 128 * 2;
    _Float16* Pi  = (_Float16*)(ws + off);           off += (size_t)ni * 128 * 2;
    _Float16* W2f = (_Float16*)(ws + off);           off += 4096 * 2;
    _Float16* W3f = (_Float16*)(ws + off);           off += 512 * 2;
    int* flag = (int*)(ws + off);

    const int nblk_d = (nd + 15) / 16;
    const int nblk_i = (ni + 15) / 16;

    node_proj2<<<nblk_d + nblk_i + 2, 256, 0, stream>>>(
        x_drug, x_dis, W1, b1, Pd, Pi, nd, ni, nblk_d, nblk_i,
        W2, W3, W2f, W3f,
        (const unsigned*)eidx, 2LL * E, flag);

    edge_mlp<<<(E + 255) / 256, 256, 0, stream>>>(eidx, Pd, Pi,
                                                  W2f, b2, W3f, b3, W4, b4,
                                                  flag, (float*)d_out, E);
}

// Round 9
// 161.196 us; speedup vs baseline: 1.0107x; 1.0107x over previous
//
#include <hip/hip_runtime.h>
#include <cstdint>
#include <cstddef>

typedef _Float16 hf2   __attribute__((ext_vector_type(2)));
typedef _Float16 f16x8 __attribute__((ext_vector_type(8)));
typedef float    f32x4 __attribute__((ext_vector_type(4)));

__device__ __forceinline__ f16x8 q2h8(uint4 q) { union { uint4 q; f16x8 h; } c; c.q = q; return c.h; }
__device__ __forceinline__ hf2 pkrtz(float lo, float hi) {
    auto v = __builtin_amdgcn_cvt_pkrtz(lo, hi);
    union { decltype(v) a; hf2 b; } c; c.a = v; return c.b;
}
__device__ __forceinline__ float lreluf(float x) { return fmaxf(x, 0.01f * x); }
// elementwise lrelu(a+b) on 8 packed f16
__device__ __forceinline__ f16x8 lrelu8(uint4 a, uint4 b) {
    f16x8 s = q2h8(a) + q2h8(b);
    f16x8 m = s * (_Float16)0.01f;
    return __builtin_elementwise_max(s, m);
}

// ---------------------------------------------------------------------------
// node projection + (extra blocks) weight packing + index-format detect.
// P[r][c] = (bias) + sum_k x[r][k] * W1[koff+k][c], stored f16.
__global__ __launch_bounds__(256) void node_proj2(
    const float* __restrict__ xd, const float* __restrict__ xi,
    const float* __restrict__ W1, const float* __restrict__ b1,
    _Float16* __restrict__ Pd, _Float16* __restrict__ Pi,
    int nd, int ni, int nblk_d, int nblk_i,
    const float* __restrict__ W2, const float* __restrict__ W3,
    _Float16* __restrict__ W2f, _Float16* __restrict__ W3f,
    const unsigned* __restrict__ ew, long long nwords, int* __restrict__ flag)
{
    const int t = threadIdx.x;
    const int nproj = nblk_d + nblk_i;

    if ((int)blockIdx.x >= nproj) {
        if ((int)blockIdx.x == nproj) {
            // W2 as MFMA B-fragments: frag(nt,kt), lane l, elem i ->
            //   B[k=kt*32+8*(l>>4)+i][col=nt*16+(l&15)]
            for (int idx = t; idx < 4096; idx += 256) {
                int i  = idx & 7;
                int l  = (idx >> 3) & 63;
                int kt = (idx >> 9) & 3;
                int nt = (idx >> 11) & 1;
                int k = kt * 32 + 8 * (l >> 4) + i;
                int j = nt * 16 + (l & 15);
                W2f[idx] = (_Float16)W2[k * 32 + j];
            }
            // W3^T as MFMA A-fragment: lane l, elem i -> W3[k=8*(l>>4)+i][row=l&15]
            for (int idx = t; idx < 512; idx += 256) {
                int i = idx & 7, l = idx >> 3;
                W3f[idx] = (_Float16)W3[(8 * (l >> 4) + i) * 16 + (l & 15)];
            }
        } else if (t < 64) {
            const long long pairs = nwords / 2;
            const long long step  = pairs / 64;
            unsigned v = 0;
            for (int s = 0; s < 4; ++s) {
                long long p = (long long)t * step + (long long)s * (step / 4 + 1);
                if (p < pairs) v |= ew[2 * p + 1];
            }
            unsigned long long ball = __ballot(v != 0);
            if (t == 0) *flag = (ball == 0ULL) ? 1 : 0;
        }
        return;
    }

    __shared__ float xs[1600];
    const int c  = t & 127;
    const int ty = t >> 7;
    const bool dis = (int)blockIdx.x >= nblk_d;
    const int b = dis ? (blockIdx.x - nblk_d) : blockIdx.x;
    const int n = dis ? ni : nd;
    const float* x = dis ? xi : xd;
    const float* W = dis ? (W1 + 100 * 128) : W1;
    _Float16* P = dis ? Pi : Pd;
    const float bv = dis ? b1[c] : 0.f;
    const int r0 = b * 16;

    const long long gbase = (long long)r0 * 100;
    const long long lim   = (long long)n * 100;
    for (int idx = t; idx < 1600; idx += 256) {
        long long g = gbase + idx;
        xs[idx] = (g < lim) ? x[g] : 0.f;
    }
    __syncthreads();

    float acc[8];
#pragma unroll
    for (int i = 0; i < 8; ++i) acc[i] = bv;

    const float4* xs4 = (const float4*)xs;
#pragma unroll 5
    for (int kk = 0; kk < 25; ++kk) {
        float w0 = W[(4 * kk + 0) * 128 + c];
        float w1 = W[(4 * kk + 1) * 128 + c];
        float w2 = W[(4 * kk + 2) * 128 + c];
        float w3 = W[(4 * kk + 3) * 128 + c];
#pragma unroll
        for (int i = 0; i < 8; ++i) {
            float4 xv = xs4[(ty * 8 + i) * 25 + kk];
            acc[i] = fmaf(xv.x, w0, acc[i]);
            acc[i] = fmaf(xv.y, w1, acc[i]);
            acc[i] = fmaf(xv.z, w2, acc[i]);
            acc[i] = fmaf(xv.w, w3, acc[i]);
        }
    }
#pragma unroll
    for (int i = 0; i < 8; ++i) {
        int r = r0 + ty * 8 + i;
        if (r < n) P[(size_t)r * 128 + c] = (_Float16)acc[i];
    }
}

// ---------------------------------------------------------------------------
// Edge MLP: 256 threads = 4 waves, each wave owns 64 edges (4 tiles of 16).
// Explicit ping-pong gather pipeline (issue q+1's 8 loads before consuming q)
// with __launch_bounds__(256,4) -> 128-VGPR budget so the loads stay in
// flight (round-7 failure mode: 52 VGPR -> serialized vmcnt(0) per pair).
// f16 LDS bounce [64][40] (20 KB), zero barriers (wave-private slabs).
__global__ __launch_bounds__(256, 4) void edge_mlp(
    const void* __restrict__ eidx_raw,
    const _Float16* __restrict__ Pd, const _Float16* __restrict__ Pi,
    const _Float16* __restrict__ W2f, const float* __restrict__ b2,
    const _Float16* __restrict__ W3f, const float* __restrict__ b3,
    const float* __restrict__ W4, const float* __restrict__ b4,
    const int* __restrict__ flag64,
    float* __restrict__ out, int E)
{
    __shared__ __align__(16) _Float16 H2[4][64 * 40];   // 20 KB total

    const int t  = threadIdx.x;
    const int l  = t & 63;
    const int w  = t >> 6;
    const int er = l & 15;
    const int cg = l >> 4;
    const int base = blockIdx.x * 256 + w * 64;
    const int e_c = min(base + l, E - 1);
    _Float16* Hw = H2[w];

    int i0, i1;
    if (*flag64) {
        const long long* p = (const long long*)eidx_raw;
        i0 = (int)p[e_c];
        i1 = (int)p[(size_t)E + e_c];
    } else {
        const int* p = (const int*)eidx_raw;
        i0 = p[e_c];
        i1 = p[(size_t)E + e_c];
    }

    // all 4 q-tile row indices up front (cheap shfl, no memory dep)
    int j0[4], j1[4];
#pragma unroll
    for (int q = 0; q < 4; ++q) {
        j0[q] = __shfl(i0, q * 16 + er, 64);
        j1[q] = __shfl(i1, q * 16 + er, 64);
    }

    // layer-2 B-fragments (32 VGPR, L2-hit)
    f16x8 bf0[4], bf1[4];
    {
        const uint4* W2q = (const uint4*)W2f;
#pragma unroll
        for (int kt = 0; kt < 4; ++kt) {
            bf0[kt] = q2h8(W2q[kt * 64 + l]);
            bf1[kt] = q2h8(W2q[256 + kt * 64 + l]);
        }
    }
    const float b2v0 = b2[er], b2v1 = b2[16 + er];

    // ---- gather + layer-2 MFMA, ping-pong pipelined over q ----
    uint4 dA[2][4], dB[2][4];
    {
        const uint4* rD = (const uint4*)(Pd + (size_t)j0[0] * 128);
        const uint4* rI = (const uint4*)(Pi + (size_t)j1[0] * 128);
#pragma unroll
        for (int kt = 0; kt < 4; ++kt) {
            dA[0][kt] = rD[kt * 4 + cg];
            dB[0][kt] = rI[kt * 4 + cg];
        }
    }

#pragma unroll
    for (int q = 0; q < 4; ++q) {
        if (q < 3) {   // issue next tile's 8 loads before consuming current
            const uint4* rD = (const uint4*)(Pd + (size_t)j0[q + 1] * 128);
            const uint4* rI = (const uint4*)(Pi + (size_t)j1[q + 1] * 128);
#pragma unroll
            for (int kt = 0; kt < 4; ++kt) {
                dA[(q + 1) & 1][kt] = rD[kt * 4 + cg];
                dB[(q + 1) & 1][kt] = rI[kt * 4 + cg];
            }
        }

        f32x4 c0 = {0.f, 0.f, 0.f, 0.f}, c1 = {0.f, 0.f, 0.f, 0.f};
#pragma unroll
        for (int kt = 0; kt < 4; ++kt) {
            f16x8 af = lrelu8(dA[q & 1][kt], dB[q & 1][kt]);
            c0 = __builtin_amdgcn_mfma_f32_16x16x32_f16(af, bf0[kt], c0, 0, 0, 0);
            c1 = __builtin_amdgcn_mfma_f32_16x16x32_f16(af, bf1[kt], c1, 0, 0, 0);
        }

        // h2 = lrelu(D + b2) -> wave-private LDS (f16, row stride 40)
#pragma unroll
        for (int r = 0; r < 4; ++r) {
            const int e = q * 16 + 4 * cg + r;
            Hw[e * 40 + er]      = (_Float16)lreluf(c0[r] + b2v0);
            Hw[e * 40 + 16 + er] = (_Float16)lreluf(c1[r] + b2v1);
        }
    }

    // ---- layer-3 MFMA (swapped operands) + layer-4 shfl reduce ----
    const f16x8 w3f = q2h8(((const uint4*)W3f)[l]);
    const float4 b3q = ((const float4*)b3)[cg];
    const float4 w4q = ((const float4*)W4)[cg];
    const float  b4v = b4[0];

#pragma unroll
    for (int q = 0; q < 4; ++q) {
        const int e2 = q * 16 + er;
        // B-frag: h2^T — lane reads h2[edge=er][8*cg..+7] as one b128
        f16x8 hv = *(const f16x8*)&Hw[e2 * 40 + 8 * cg];

        // D3 = W3^T · h2^T : lane holds D3[j3=4*cg+r][edge=er]
        f32x4 d3 = __builtin_amdgcn_mfma_f32_16x16x32_f16(
            w3f, hv, (f32x4){0.f, 0.f, 0.f, 0.f}, 0, 0, 0);

        float v = lreluf(d3[0] + b3q.x) * w4q.x;
        v      += lreluf(d3[1] + b3q.y) * w4q.y;
        v      += lreluf(d3[2] + b3q.z) * w4q.z;
        v      += lreluf(d3[3] + b3q.w) * w4q.w;
        v += __shfl_xor(v, 16, 64);
        v += __shfl_xor(v, 32, 64);

        if (cg == 0) {
            const int eo = base + q * 16 + er;
            if (eo < E) out[eo] = v + b4v;
        }
    }
}

// ---------------------------------------------------------------------------
extern "C" void kernel_launch(void* const* d_in, const int* in_sizes, int n_in,
                              void* d_out, int out_size, void* d_ws, size_t ws_size,
                              hipStream_t stream)
{
    const float* x_drug = (const float*)d_in[0];
    const float* x_dis  = (const float*)d_in[1];
    const void*  eidx   = d_in[2];
    const float* W1 = (const float*)d_in[3];
    const float* b1 = (const float*)d_in[4];
    const float* W2 = (const float*)d_in[5];
    const float* b2 = (const float*)d_in[6];
    const float* W3 = (const float*)d_in[7];
    const float* b3 = (const float*)d_in[8];
    const float* W4 = (const float*)d_in[9];
    const float* b4 = (const float*)d_in[10];

    const int nd = in_sizes[0] / 100;
    const int ni = in_sizes[1] / 100;
    const int E  = in_sizes[2] / 2;

    char* ws = (char*)d_ws;
    _Float16* Pd  = (_Float16*)ws;                   size_t off = (size_t)nd * 128 * 2;
    _Float16* Pi  = (_Float16*)(ws + off);           off += (size_t)ni * 128 * 2;
    _Float16* W2f = (_Float16*)(ws + off);           off += 4096 * 2;
    _Float16* W3f = (_Float16*)(ws + off);           off += 512 * 2;
    int* flag = (int*)(ws + off);

    const int nblk_d = (nd + 15) / 16;
    const int nblk_i = (ni + 15) / 16;

    node_proj2<<<nblk_d + nblk_i + 2, 256, 0, stream>>>(
        x_drug, x_dis, W1, b1, Pd, Pi, nd, ni, nblk_d, nblk_i,
        W2, W3, W2f, W3f,
        (const unsigned*)eidx, 2LL * E, flag);

    edge_mlp<<<(E + 255) / 256, 256, 0, stream>>>(eidx, Pd, Pi,
                                                  W2f, b2, W3f, b3, W4, b4,
                                                  flag, (float*)d_out, E);
}